// Round 7
// baseline (294.761 us; speedup 1.0000x reference)
//
#include <hip/hip_runtime.h>
#include <hip/hip_bf16.h>
#include <math.h>

#define C_DIM 192
#define NTOK 16384
#define NB 16
#define NH 8
#define HD 24
#define EPSN 1e-12f

typedef float f32x4 __attribute__((ext_vector_type(4)));
typedef __bf16 bf16x4 __attribute__((ext_vector_type(4)));
typedef __bf16 bf16x8 __attribute__((ext_vector_type(8)));

__device__ __forceinline__ f32x4 mfma16(bf16x8 a, bf16x8 b, f32x4 c) {
  return __builtin_amdgcn_mfma_f32_16x16x32_bf16(a, b, c, 0, 0, 0);
}

// load 8 consecutive f32 (16B-aligned x2) and convert to 8 bf16
__device__ __forceinline__ bf16x8 cvt8(const float* __restrict__ p) {
  f32x4 a = *(const f32x4*)p;
  f32x4 b = *(const f32x4*)(p + 4);
  bf16x8 r;
  r[0] = (__bf16)a[0]; r[1] = (__bf16)a[1]; r[2] = (__bf16)a[2]; r[3] = (__bf16)a[3];
  r[4] = (__bf16)b[0]; r[5] = (__bf16)b[1]; r[6] = (__bf16)b[2]; r[7] = (__bf16)b[3];
  return r;
}

// ---------------- K1: partial Gram + bf16 x-echo ----------------------------
// While staging x chunks to LDS (bf16), also write the bf16 copy to xb16
// (64B-aligned 64B runs, coalesced). K3 consumes xb16 -> its read halves.
__global__ __launch_bounds__(256, 2) void k1_gram(const float* __restrict__ x,
                                                  float* __restrict__ gpart,
                                                  __bf16* __restrict__ xb16,
                                                  int kc) {
  const int b = blockIdx.y, chunk = blockIdx.x;
  const float* xb = x + (size_t)b * C_DIM * NTOK + (size_t)chunk * kc;
  __bf16* xbb = xb16 + (size_t)b * C_DIM * NTOK + (size_t)chunk * kc;
  __shared__ __bf16 xsh[2][C_DIM * 40];  // 2 x 15KB
  const int t = threadIdx.x;
  const int lane = t & 63, wid = t >> 6;
  const int lrow = lane & 15, loct = lane >> 4;
  const int r0 = (wid >> 1) * 96, c0 = (wid & 1) * 96;
  f32x4 acc[6][6] = {};
  f32x4 stg[6];

#pragma unroll
  for (int it = 0; it < 6; ++it) {
    int idx = it * 256 + t, r = idx >> 3, c8 = idx & 7;
    stg[it] = *(const f32x4*)(xb + (size_t)r * NTOK + 4 * c8);
  }
#pragma unroll
  for (int it = 0; it < 6; ++it) {
    int idx = it * 256 + t, r = idx >> 3, c8 = idx & 7;
    bf16x4 w;
    w[0] = (__bf16)stg[it][0]; w[1] = (__bf16)stg[it][1];
    w[2] = (__bf16)stg[it][2]; w[3] = (__bf16)stg[it][3];
    *(bf16x4*)(&xsh[0][r * 40 + 4 * c8]) = w;
    *(bf16x4*)(xbb + (size_t)r * NTOK + 4 * c8) = w;
  }
  __syncthreads();

  for (int ks = 0; ks < kc; ks += 32) {
    const int cur = (ks >> 5) & 1;
    const bool more = (ks + 32) < kc;
    if (more) {
#pragma unroll
      for (int it = 0; it < 6; ++it) {
        int idx = it * 256 + t, r = idx >> 3, c8 = idx & 7;
        stg[it] = *(const f32x4*)(xb + (size_t)r * NTOK + ks + 32 + 4 * c8);
      }
    }
    bf16x8 fa[6];
#pragma unroll
    for (int i = 0; i < 6; ++i)
      fa[i] = *(const bf16x8*)(&xsh[cur][(r0 + 16 * i + lrow) * 40 + 8 * loct]);
#pragma unroll
    for (int j = 0; j < 6; ++j) {
      bf16x8 fb = *(const bf16x8*)(&xsh[cur][(c0 + 16 * j + lrow) * 40 + 8 * loct]);
#pragma unroll
      for (int i = 0; i < 6; ++i) acc[i][j] = mfma16(fa[i], fb, acc[i][j]);
    }
    if (more) {
#pragma unroll
      for (int it = 0; it < 6; ++it) {
        int idx = it * 256 + t, r = idx >> 3, c8 = idx & 7;
        bf16x4 w;
        w[0] = (__bf16)stg[it][0]; w[1] = (__bf16)stg[it][1];
        w[2] = (__bf16)stg[it][2]; w[3] = (__bf16)stg[it][3];
        *(bf16x4*)(&xsh[cur ^ 1][r * 40 + 4 * c8]) = w;
        *(bf16x4*)(xbb + (size_t)r * NTOK + ks + 32 + 4 * c8) = w;
      }
    }
    __syncthreads();
  }
  float* gp = gpart + ((size_t)chunk * NB + b) * C_DIM * C_DIM;
#pragma unroll
  for (int i = 0; i < 6; ++i)
#pragma unroll
    for (int j = 0; j < 6; ++j)
#pragma unroll
      for (int e = 0; e < 4; ++e)
        gp[(size_t)(r0 + 16 * i + 4 * loct + e) * C_DIM + (c0 + 16 * j + lrow)] =
            acc[i][j][e];
}

// ---------------- K2a: reduce partials -> G ---------------------------------
__global__ __launch_bounds__(256) void k2a_reduce(const float* __restrict__ gpart,
                                                  float* __restrict__ G,
                                                  int nchunk) {
  const size_t total = (size_t)NB * C_DIM * C_DIM;
  size_t e0 = ((size_t)blockIdx.x * 256 + threadIdx.x) * 4;
  f32x4 s = {};
  for (int c = 0; c < nchunk; ++c) s += *(const f32x4*)(gpart + c * total + e0);
  *(f32x4*)(G + e0) = s;
}

// ---------------- K2b1: Tt[b] = [Wq|Wk]^T @ G  (384x192), uses G symmetry ---
__global__ __launch_bounds__(256) void k2b1_t(const float* __restrict__ G,
                                              const float* __restrict__ wqkv,
                                              float* __restrict__ Tt) {
  const int b = blockIdx.y, rb = blockIdx.x;  // rb 0..5 -> 64 rows
  const int lane = threadIdx.x & 63, wid = threadIdx.x >> 6;
  const int lrow = lane & 15, loct = lane >> 4;
  const float* Gb = G + (size_t)b * C_DIM * C_DIM;
  const int ddA = rb * 64 + wid * 16 + lrow;  // < 384, == wqkv column index
  f32x4 acc[12] = {};
  for (int s = 0; s < 6; ++s) {
    bf16x8 fa;
#pragma unroll
    for (int e = 0; e < 8; ++e)
      fa[e] = (__bf16)wqkv[(size_t)(32 * s + 8 * loct + e) * 576 + ddA];
#pragma unroll
    for (int j = 0; j < 12; ++j) {
      bf16x8 fb = cvt8(Gb + (size_t)(16 * j + lrow) * C_DIM + 32 * s + 8 * loct);
      acc[j] = mfma16(fa, fb, acc[j]);
    }
  }
  float* To = Tt + (size_t)b * 384 * C_DIM;
#pragma unroll
  for (int j = 0; j < 12; ++j)
#pragma unroll
    for (int e = 0; e < 4; ++e)
      To[(size_t)(rb * 64 + wid * 16 + 4 * loct + e) * C_DIM + 16 * j + lrow] =
          acc[j][e];
}

// ---------------- K2b2: per (b,h): S, norms, softmax, Yt -------------------
__global__ __launch_bounds__(256) void k2b2_attn(const float* __restrict__ Tt,
                                                 const float* __restrict__ wqkv,
                                                 const float* __restrict__ temp,
                                                 float* __restrict__ Yt) {
  const int b = blockIdx.y, h = blockIdx.x;
  __shared__ float SL[32][33];
  __shared__ float qn2L[HD], kn2L[HD];
  const int t = threadIdx.x;
  const int lane = t & 63, wid = t >> 6;
  const int lrow = lane & 15, loct = lane >> 4;
  const float* Tb = Tt + (size_t)b * 384 * C_DIM;
  const int r = wid >> 1, j = wid & 1;  // 2x2 tiles cover 32x32 (clip to 24x24)
  f32x4 acc = {};
  for (int s = 0; s < 6; ++s) {
    bf16x8 fa = cvt8(Tb + (size_t)(h * HD + 16 * r + lrow) * C_DIM + 32 * s + 8 * loct);
    bf16x8 fb;
#pragma unroll
    for (int e = 0; e < 8; ++e)
      fb[e] = (__bf16)wqkv[(size_t)(32 * s + 8 * loct + e) * 576 + 192 + h * HD +
                           16 * j + lrow];
    acc = mfma16(fa, fb, acc);
  }
#pragma unroll
  for (int e = 0; e < 4; ++e) {
    int d = 16 * r + 4 * loct + e, ee = 16 * j + lrow;
    if (d < HD && ee < HD) SL[d][ee] = acc[e];
  }
  if (t < 48) {  // squared norms: diag of Wq^T G Wq / Wk^T G Wk
    const int dd = (t < 24) ? t : t - 24;
    const int row = ((t < 24) ? 0 : 192) + h * HD + dd;
    float s = 0.f;
    for (int c = 0; c < C_DIM; ++c)
      s += Tb[(size_t)row * C_DIM + c] * wqkv[(size_t)c * 576 + row];
    if (t < 24) qn2L[dd] = s; else kn2L[dd] = s;
  }
  __syncthreads();
  if (t < HD) {  // softmax row t
    const float tp = temp[h];
    float nq = fmaxf(sqrtf(fmaxf(qn2L[t], 0.f)), EPSN);
    float lg[HD];
    float m = -1e30f;
#pragma unroll
    for (int e = 0; e < HD; ++e) {
      float nk = fmaxf(sqrtf(fmaxf(kn2L[e], 0.f)), EPSN);
      lg[e] = SL[t][e] / (nq * nk) * tp;
      m = fmaxf(m, lg[e]);
    }
    float sum = 0.f;
#pragma unroll
    for (int e = 0; e < HD; ++e) { lg[e] = __expf(lg[e] - m); sum += lg[e]; }
    float inv = 1.f / sum;
#pragma unroll
    for (int e = 0; e < HD; ++e) SL[t][e] = lg[e] * inv;
  }
  __syncthreads();
  if (t < C_DIM) {  // Yt[b][ci=t][h*24+d] = sum_e attn[d][e] * Wv[t][e]
    float wv[HD];
#pragma unroll
    for (int e = 0; e < HD; ++e)
      wv[e] = wqkv[(size_t)t * 576 + 384 + h * HD + e];
    float* Yo = Yt + ((size_t)b * C_DIM + t) * C_DIM + h * HD;
#pragma unroll
    for (int d = 0; d < HD; ++d) {
      float y = 0.f;
#pragma unroll
      for (int e = 0; e < HD; ++e) y += SL[d][e] * wv[e];
      Yo[d] = y;
    }
  }
}

// ---------------- K2c: M[b] = Wproj^T @ Y  (bf16 out) -----------------------
__global__ __launch_bounds__(256) void k2c_m(const float* __restrict__ wproj,
                                             const float* __restrict__ Yt,
                                             __bf16* __restrict__ M) {
  const int b = blockIdx.y, rb = blockIdx.x;  // rb 0..2 -> 64 rows
  const int lane = threadIdx.x & 63, wid = threadIdx.x >> 6;
  const int lrow = lane & 15, loct = lane >> 4;
  const float* Yb = Yt + (size_t)b * C_DIM * C_DIM;
  const int coA = rb * 64 + wid * 16 + lrow;
  f32x4 acc[12] = {};
  for (int s = 0; s < 6; ++s) {
    bf16x8 fa;
#pragma unroll
    for (int e = 0; e < 8; ++e)
      fa[e] = (__bf16)wproj[(size_t)(32 * s + 8 * loct + e) * C_DIM + coA];
#pragma unroll
    for (int j = 0; j < 12; ++j) {
      bf16x8 fb = cvt8(Yb + (size_t)(16 * j + lrow) * C_DIM + 32 * s + 8 * loct);
      acc[j] = mfma16(fa, fb, acc[j]);
    }
  }
  __bf16* Mo = M + (size_t)b * C_DIM * C_DIM;
#pragma unroll
  for (int j = 0; j < 12; ++j)
#pragma unroll
    for (int e = 0; e < 4; ++e)
      Mo[(size_t)(rb * 64 + wid * 16 + 4 * loct + e) * C_DIM + 16 * j + lrow] =
          (__bf16)acc[j][e];
}

// ---------------- K3 v7: out[b] = M[b] @ xb16[b] + bias ---------------------
// Full M (192x192) in 72KB swizzled LDS; x read ONCE as bf16 (100MB total).
// Block = 192 rows x 128 tokens; wave owns 48 rows x 128 tokens (acc 96).
// Depth-2 register prefetch of the 8B bf16x4 token loads. Epilogue: per-wave
// LDS transpose (stride 132) -> 512B-contiguous dwordx4 store runs.
__global__ __launch_bounds__(256, 2) void k3_out(const __bf16* __restrict__ xb16,
                                                 const __bf16* __restrict__ M,
                                                 const float* __restrict__ bproj,
                                                 float* __restrict__ out) {
  const int nt = blockIdx.x, b = blockIdx.y;
  __shared__ __bf16 Ml[C_DIM * C_DIM];  // 73728B; epi overlays after main loop
  __shared__ float biasL[C_DIM];
  const int t = threadIdx.x;
  const int lane = t & 63, w = t >> 6;
  const int lrow = lane & 15, loct = lane >> 4;

  const __bf16* Mb = M + (size_t)b * C_DIM * C_DIM;
  for (int i = t; i < C_DIM * 24; i += 256) {
    int row = i / 24, ch = i % 24;
    bf16x8 v = *(const bf16x8*)(Mb + row * C_DIM + ch * 8);
    *(bf16x8*)(Ml + row * C_DIM + ((ch ^ (row & 7)) * 8)) = v;
  }
  if (t < C_DIM) biasL[t] = bproj[t];

  const __bf16* xr = xb16 + (size_t)b * C_DIM * NTOK + nt * 128;
  float* ob = out + (size_t)b * C_DIM * NTOK + nt * 128;

  f32x4 acc[3][2][4] = {};   // [tt][h][nf]: row 48w+16tt+4loct+e, tok 64h+4lrow+nf
  bf16x4 ld[3][2][8];        // rotating prefetch: [buf][h][ch e]

#define K3_LOAD(buf, s)                                                        \
  {                                                                            \
    _Pragma("unroll") for (int h = 0; h < 2; ++h)                              \
        _Pragma("unroll") for (int e = 0; e < 8; ++e)                          \
            ld[buf][h][e] = *(const bf16x4*)(xr +                              \
                (size_t)(32 * (s) + 8 * loct + e) * NTOK + 64 * h + 4 * lrow); \
  }

  K3_LOAD(0, 0);
  K3_LOAD(1, 1);
  __syncthreads();  // Ml + biasL ready

#pragma unroll
  for (int s = 0; s < 6; ++s) {
    const int cur = s % 3, nxt = (s + 2) % 3;
    if (s < 4) K3_LOAD(nxt, s + 2);
    bf16x8 fa[3];
#pragma unroll
    for (int tt = 0; tt < 3; ++tt) {
      int rowb = 48 * w + 16 * tt + lrow;
      fa[tt] = *(const bf16x8*)(Ml + rowb * C_DIM +
                                (((4 * s + loct) ^ (rowb & 7)) * 8));
    }
#pragma unroll
    for (int h = 0; h < 2; ++h)
#pragma unroll
      for (int nf = 0; nf < 4; ++nf) {
        bf16x8 fb;
#pragma unroll
        for (int e = 0; e < 8; ++e) fb[e] = ld[cur][h][e][nf];
#pragma unroll
        for (int tt = 0; tt < 3; ++tt)
          acc[tt][h][nf] = mfma16(fa[tt], fb, acc[tt][h][nf]);
      }
  }
#undef K3_LOAD

  __syncthreads();  // all waves done reading Ml; safe to overlay epi
  // per-wave transpose buffer: 16 rows x 132 f32 (8448B), inside Ml region
  float* epi_w = (float*)Ml + w * 2112;
#pragma unroll
  for (int tt = 0; tt < 3; ++tt) {
#pragma unroll
    for (int h = 0; h < 2; ++h)
#pragma unroll
      for (int e = 0; e < 4; ++e) {
        const float br = biasL[48 * w + 16 * tt + 4 * loct + e];
        f32x4 v;
        v[0] = acc[tt][h][0][e] + br;
        v[1] = acc[tt][h][1][e] + br;
        v[2] = acc[tt][h][2][e] + br;
        v[3] = acc[tt][h][3][e] + br;
        *(f32x4*)(epi_w + (4 * loct + e) * 132 + 64 * h + 4 * lrow) = v;
      }
    // wave-local ds_write -> ds_read ordered by program order, no barrier
#pragma unroll
    for (int i = 0; i < 8; ++i) {
      int rl = 2 * i + (lane >> 5);
      int c4 = 4 * (lane & 31);
      f32x4 v = *(const f32x4*)(epi_w + rl * 132 + c4);
      *(f32x4*)(ob + (size_t)(48 * w + 16 * tt + rl) * NTOK + c4) = v;
    }
  }
}

extern "C" void kernel_launch(void* const* d_in, const int* in_sizes, int n_in,
                              void* d_out, int out_size, void* d_ws, size_t ws_size,
                              hipStream_t stream) {
  const float* x = (const float*)d_in[0];
  const float* wqkv = (const float*)d_in[1];
  const float* wproj = (const float*)d_in[2];
  const float* bproj = (const float*)d_in[3];
  const float* temp = (const float*)d_in[4];
  float* out = (float*)d_out;

  const size_t XB16 = (size_t)NB * C_DIM * NTOK;  // bf16 elems (100.7 MB)
  const size_t GSZ = (size_t)NB * C_DIM * C_DIM;  // 589824 floats
  const size_t TSZ = (size_t)NB * 384 * C_DIM;    // 1179648 floats
  int nchunk = 32;
  while (nchunk > 1 &&
         XB16 * 2 + ((size_t)nchunk * GSZ + GSZ + TSZ + GSZ + GSZ) * 4 > ws_size)
    nchunk >>= 1;
  __bf16* xb16 = (__bf16*)d_ws;
  float* wsf = (float*)d_ws + XB16 / 2;
  float* gpart = wsf;
  float* G = gpart + (size_t)nchunk * GSZ;
  float* Tt = G + GSZ;
  float* Yt = Tt + TSZ;
  __bf16* M = (__bf16*)(Yt + GSZ);

  k1_gram<<<dim3(nchunk, NB), 256, 0, stream>>>(x, gpart, xb16, NTOK / nchunk);
  k2a_reduce<<<dim3(576), 256, 0, stream>>>(gpart, G, nchunk);
  k2b1_t<<<dim3(6, NB), 256, 0, stream>>>(G, wqkv, Tt);
  k2b2_attn<<<dim3(NH, NB), 256, 0, stream>>>(Tt, wqkv, temp, Yt);
  k2c_m<<<dim3(3, NB), 256, 0, stream>>>(wproj, Yt, M);
  k3_out<<<dim3(NTOK / 128, NB), 256, 0, stream>>>(xb16, M, bproj, out);
}

// Round 8
// 249.954 us; speedup vs baseline: 1.1793x; 1.1793x over previous
//
#include <hip/hip_runtime.h>
#include <hip/hip_bf16.h>
#include <math.h>

#define C_DIM 192
#define NTOK 16384
#define NB 16
#define NH 8
#define HD 24
#define EPSN 1e-12f

typedef float f32x4 __attribute__((ext_vector_type(4)));
typedef __bf16 bf16x4 __attribute__((ext_vector_type(4)));
typedef __bf16 bf16x8 __attribute__((ext_vector_type(8)));

__device__ __forceinline__ f32x4 mfma16(bf16x8 a, bf16x8 b, f32x4 c) {
  return __builtin_amdgcn_mfma_f32_16x16x32_bf16(a, b, c, 0, 0, 0);
}

// load 8 consecutive f32 (16B-aligned x2) and convert to 8 bf16
__device__ __forceinline__ bf16x8 cvt8(const float* __restrict__ p) {
  f32x4 a = *(const f32x4*)p;
  f32x4 b = *(const f32x4*)(p + 4);
  bf16x8 r;
  r[0] = (__bf16)a[0]; r[1] = (__bf16)a[1]; r[2] = (__bf16)a[2]; r[3] = (__bf16)a[3];
  r[4] = (__bf16)b[0]; r[5] = (__bf16)b[1]; r[6] = (__bf16)b[2]; r[7] = (__bf16)b[3];
  return r;
}

// ---------------- K1: partial Gram, 8 waves/block for 16 waves/CU -----------
// 512 threads, wave-tile 48x96 (acc 72 VGPR), LDS 30KB dbuf -> 2 blocks/CU.
__global__ __launch_bounds__(512, 4) void k1_gram(const float* __restrict__ x,
                                                  float* __restrict__ gpart,
                                                  int kc) {
  const int b = blockIdx.y, chunk = blockIdx.x;
  const float* xb = x + (size_t)b * C_DIM * NTOK + (size_t)chunk * kc;
  __shared__ __bf16 xsh[2][C_DIM * 40];  // 2 x 15KB, stride 40 (conflict-light)
  const int t = threadIdx.x;
  const int lane = t & 63, wid = t >> 6;  // wid 0..7
  const int lrow = lane & 15, loct = lane >> 4;
  const int r0 = (wid >> 1) * 48, c0 = (wid & 1) * 96;
  f32x4 acc[3][6] = {};
  f32x4 stg[3];

#pragma unroll
  for (int it = 0; it < 3; ++it) {
    int idx = it * 512 + t, r = idx >> 3, c8 = idx & 7;
    stg[it] = *(const f32x4*)(xb + (size_t)r * NTOK + 4 * c8);
  }
#pragma unroll
  for (int it = 0; it < 3; ++it) {
    int idx = it * 512 + t, r = idx >> 3, c8 = idx & 7;
    bf16x4 w;
    w[0] = (__bf16)stg[it][0]; w[1] = (__bf16)stg[it][1];
    w[2] = (__bf16)stg[it][2]; w[3] = (__bf16)stg[it][3];
    *(bf16x4*)(&xsh[0][r * 40 + 4 * c8]) = w;
  }
  __syncthreads();

  for (int ks = 0; ks < kc; ks += 32) {
    const int cur = (ks >> 5) & 1;
    const bool more = (ks + 32) < kc;
    if (more) {
#pragma unroll
      for (int it = 0; it < 3; ++it) {
        int idx = it * 512 + t, r = idx >> 3, c8 = idx & 7;
        stg[it] = *(const f32x4*)(xb + (size_t)r * NTOK + ks + 32 + 4 * c8);
      }
    }
    bf16x8 fa[3];
#pragma unroll
    for (int i = 0; i < 3; ++i)
      fa[i] = *(const bf16x8*)(&xsh[cur][(r0 + 16 * i + lrow) * 40 + 8 * loct]);
#pragma unroll
    for (int j = 0; j < 6; ++j) {
      bf16x8 fb = *(const bf16x8*)(&xsh[cur][(c0 + 16 * j + lrow) * 40 + 8 * loct]);
#pragma unroll
      for (int i = 0; i < 3; ++i) acc[i][j] = mfma16(fa[i], fb, acc[i][j]);
    }
    if (more) {
#pragma unroll
      for (int it = 0; it < 3; ++it) {
        int idx = it * 512 + t, r = idx >> 3, c8 = idx & 7;
        bf16x4 w;
        w[0] = (__bf16)stg[it][0]; w[1] = (__bf16)stg[it][1];
        w[2] = (__bf16)stg[it][2]; w[3] = (__bf16)stg[it][3];
        *(bf16x4*)(&xsh[cur ^ 1][r * 40 + 4 * c8]) = w;
      }
    }
    __syncthreads();
  }
  float* gp = gpart + ((size_t)chunk * NB + b) * C_DIM * C_DIM;
#pragma unroll
  for (int i = 0; i < 3; ++i)
#pragma unroll
    for (int j = 0; j < 6; ++j)
#pragma unroll
      for (int e = 0; e < 4; ++e)
        gp[(size_t)(r0 + 16 * i + 4 * loct + e) * C_DIM + (c0 + 16 * j + lrow)] =
            acc[i][j][e];
}

// ---------------- K2a: reduce partials -> G ---------------------------------
__global__ __launch_bounds__(256) void k2a_reduce(const float* __restrict__ gpart,
                                                  float* __restrict__ G,
                                                  int nchunk) {
  const size_t total = (size_t)NB * C_DIM * C_DIM;
  size_t e0 = ((size_t)blockIdx.x * 256 + threadIdx.x) * 4;
  f32x4 s = {};
  for (int c = 0; c < nchunk; ++c) s += *(const f32x4*)(gpart + c * total + e0);
  *(f32x4*)(G + e0) = s;
}

// ---------------- K2b1: Tt[b] = [Wq|Wk]^T @ G  (384x192), uses G symmetry ---
__global__ __launch_bounds__(256) void k2b1_t(const float* __restrict__ G,
                                              const float* __restrict__ wqkv,
                                              float* __restrict__ Tt) {
  const int b = blockIdx.y, rb = blockIdx.x;  // rb 0..5 -> 64 rows
  const int lane = threadIdx.x & 63, wid = threadIdx.x >> 6;
  const int lrow = lane & 15, loct = lane >> 4;
  const float* Gb = G + (size_t)b * C_DIM * C_DIM;
  const int ddA = rb * 64 + wid * 16 + lrow;  // < 384, == wqkv column index
  f32x4 acc[12] = {};
  for (int s = 0; s < 6; ++s) {
    bf16x8 fa;
#pragma unroll
    for (int e = 0; e < 8; ++e)
      fa[e] = (__bf16)wqkv[(size_t)(32 * s + 8 * loct + e) * 576 + ddA];
#pragma unroll
    for (int j = 0; j < 12; ++j) {
      bf16x8 fb = cvt8(Gb + (size_t)(16 * j + lrow) * C_DIM + 32 * s + 8 * loct);
      acc[j] = mfma16(fa, fb, acc[j]);
    }
  }
  float* To = Tt + (size_t)b * 384 * C_DIM;
#pragma unroll
  for (int j = 0; j < 12; ++j)
#pragma unroll
    for (int e = 0; e < 4; ++e)
      To[(size_t)(rb * 64 + wid * 16 + 4 * loct + e) * C_DIM + 16 * j + lrow] =
          acc[j][e];
}

// ---------------- K2b2: per (b,h): S, norms, softmax, Yt -------------------
__global__ __launch_bounds__(256) void k2b2_attn(const float* __restrict__ Tt,
                                                 const float* __restrict__ wqkv,
                                                 const float* __restrict__ temp,
                                                 float* __restrict__ Yt) {
  const int b = blockIdx.y, h = blockIdx.x;
  __shared__ float SL[32][33];
  __shared__ float qn2L[HD], kn2L[HD];
  const int t = threadIdx.x;
  const int lane = t & 63, wid = t >> 6;
  const int lrow = lane & 15, loct = lane >> 4;
  const float* Tb = Tt + (size_t)b * 384 * C_DIM;
  const int r = wid >> 1, j = wid & 1;  // 2x2 tiles cover 32x32 (clip to 24x24)
  f32x4 acc = {};
  for (int s = 0; s < 6; ++s) {
    bf16x8 fa = cvt8(Tb + (size_t)(h * HD + 16 * r + lrow) * C_DIM + 32 * s + 8 * loct);
    bf16x8 fb;
#pragma unroll
    for (int e = 0; e < 8; ++e)
      fb[e] = (__bf16)wqkv[(size_t)(32 * s + 8 * loct + e) * 576 + 192 + h * HD +
                           16 * j + lrow];
    acc = mfma16(fa, fb, acc);
  }
#pragma unroll
  for (int e = 0; e < 4; ++e) {
    int d = 16 * r + 4 * loct + e, ee = 16 * j + lrow;
    if (d < HD && ee < HD) SL[d][ee] = acc[e];
  }
  if (t < 48) {  // squared norms: diag of Wq^T G Wq / Wk^T G Wk
    const int dd = (t < 24) ? t : t - 24;
    const int row = ((t < 24) ? 0 : 192) + h * HD + dd;
    float s = 0.f;
    for (int c = 0; c < C_DIM; ++c)
      s += Tb[(size_t)row * C_DIM + c] * wqkv[(size_t)c * 576 + row];
    if (t < 24) qn2L[dd] = s; else kn2L[dd] = s;
  }
  __syncthreads();
  if (t < HD) {  // softmax row t
    const float tp = temp[h];
    float nq = fmaxf(sqrtf(fmaxf(qn2L[t], 0.f)), EPSN);
    float lg[HD];
    float m = -1e30f;
#pragma unroll
    for (int e = 0; e < HD; ++e) {
      float nk = fmaxf(sqrtf(fmaxf(kn2L[e], 0.f)), EPSN);
      lg[e] = SL[t][e] / (nq * nk) * tp;
      m = fmaxf(m, lg[e]);
    }
    float sum = 0.f;
#pragma unroll
    for (int e = 0; e < HD; ++e) { lg[e] = __expf(lg[e] - m); sum += lg[e]; }
    float inv = 1.f / sum;
#pragma unroll
    for (int e = 0; e < HD; ++e) SL[t][e] = lg[e] * inv;
  }
  __syncthreads();
  if (t < C_DIM) {  // Yt[b][ci=t][h*24+d] = sum_e attn[d][e] * Wv[t][e]
    float wv[HD];
#pragma unroll
    for (int e = 0; e < HD; ++e)
      wv[e] = wqkv[(size_t)t * 576 + 384 + h * HD + e];
    float* Yo = Yt + ((size_t)b * C_DIM + t) * C_DIM + h * HD;
#pragma unroll
    for (int d = 0; d < HD; ++d) {
      float y = 0.f;
#pragma unroll
      for (int e = 0; e < HD; ++e) y += SL[d][e] * wv[e];
      Yo[d] = y;
    }
  }
}

// ---------------- K2c: M[b] = Wproj^T @ Y  (bf16 out) -----------------------
__global__ __launch_bounds__(256) void k2c_m(const float* __restrict__ wproj,
                                             const float* __restrict__ Yt,
                                             __bf16* __restrict__ M) {
  const int b = blockIdx.y, rb = blockIdx.x;  // rb 0..2 -> 64 rows
  const int lane = threadIdx.x & 63, wid = threadIdx.x >> 6;
  const int lrow = lane & 15, loct = lane >> 4;
  const float* Yb = Yt + (size_t)b * C_DIM * C_DIM;
  const int coA = rb * 64 + wid * 16 + lrow;
  f32x4 acc[12] = {};
  for (int s = 0; s < 6; ++s) {
    bf16x8 fa;
#pragma unroll
    for (int e = 0; e < 8; ++e)
      fa[e] = (__bf16)wproj[(size_t)(32 * s + 8 * loct + e) * C_DIM + coA];
#pragma unroll
    for (int j = 0; j < 12; ++j) {
      bf16x8 fb = cvt8(Yb + (size_t)(16 * j + lrow) * C_DIM + 32 * s + 8 * loct);
      acc[j] = mfma16(fa, fb, acc[j]);
    }
  }
  __bf16* Mo = M + (size_t)b * C_DIM * C_DIM;
#pragma unroll
  for (int j = 0; j < 12; ++j)
#pragma unroll
    for (int e = 0; e < 4; ++e)
      Mo[(size_t)(rb * 64 + wid * 16 + 4 * loct + e) * C_DIM + 16 * j + lrow] =
          (__bf16)acc[j][e];
}

// ---------------- K3 v8: out[b] = M[b] @ x[b] + bias ------------------------
// v6 structure (half-M swizzled LDS + interleaved f32x4 x-loads + LDS
// transpose epilogue) with wave tile 48x64 (acc 48 VGPR) so that
// launch_bounds(256,4) yields 4 blocks/CU x 4 waves = 16 waves/CU.
// half is the fastest grid dim so both halves of a token window share x in L2.
__global__ __launch_bounds__(256, 4) void k3_out(const float* __restrict__ x,
                                                 const __bf16* __restrict__ M,
                                                 const float* __restrict__ bproj,
                                                 float* __restrict__ out) {
  const int half = blockIdx.x, nt = blockIdx.y, b = blockIdx.z;
  const int rbase = half * 96;
  __shared__ __bf16 Ml[96 * C_DIM];  // 36864B; overlaid by epi after main loop
  __shared__ float biasL[96];
  const int t = threadIdx.x;
  const int lane = t & 63, w = t >> 6;
  const int lrow = lane & 15, loct = lane >> 4;

  const __bf16* Mb = M + (size_t)b * C_DIM * C_DIM + (size_t)rbase * C_DIM;
  for (int i = t; i < 96 * 24; i += 256) {
    int row = i / 24, ch = i % 24;
    bf16x8 v = *(const bf16x8*)(Mb + row * C_DIM + ch * 8);
    *(bf16x8*)(Ml + row * C_DIM + ((ch ^ (row & 7)) * 8)) = v;
  }
  if (t < 96) biasL[t] = bproj[rbase + t];
  __syncthreads();

  const float* xb = x + (size_t)b * C_DIM * NTOK;
  float* ob = out + (size_t)b * C_DIM * NTOK;
  const int rw0 = (w >> 1) * 48;          // wave rows within the 96-half
  const int n0 = nt * 128 + (w & 1) * 64; // wave 64-token window

  f32x4 acc[3][4] = {};
  f32x4 xs4[8];  // prefetch: slab's 8 ch-groups x 4 consecutive tokens
#pragma unroll
  for (int e = 0; e < 8; ++e)
    xs4[e] = *(const f32x4*)(xb + (size_t)(8 * loct + e) * NTOK + n0 + 4 * lrow);

  for (int s = 0; s < 6; ++s) {
    bf16x8 fb[4];  // fb[nf][e] = x[ch=32s+8loct+e][tok=n0+4*lrow+nf]
#pragma unroll
    for (int nf = 0; nf < 4; ++nf)
#pragma unroll
      for (int e = 0; e < 8; ++e)
        fb[nf][e] = (__bf16)xs4[e][nf];
    if (s < 5) {
#pragma unroll
      for (int e = 0; e < 8; ++e)
        xs4[e] = *(const f32x4*)(xb + (size_t)(32 * (s + 1) + 8 * loct + e) * NTOK +
                                 n0 + 4 * lrow);
    }
#pragma unroll
    for (int tt = 0; tt < 3; ++tt) {
      int rowb = rw0 + 16 * tt + lrow;
      bf16x8 fa = *(const bf16x8*)(Ml + rowb * C_DIM +
                                   (((4 * s + loct) ^ (rowb & 7)) * 8));
#pragma unroll
      for (int nf = 0; nf < 4; ++nf)
        acc[tt][nf] = mfma16(fa, fb[nf], acc[tt][nf]);
    }
  }

  __syncthreads();  // all waves done reading Ml; safe to overlay epi
  // per-wave transpose buffer: 16 rows x 64 tokens, stride 68 f32
  float* epi_w = (float*)Ml + w * 1088;
#pragma unroll
  for (int tt = 0; tt < 3; ++tt) {
    f32x4 bias4 = *(const f32x4*)(biasL + rw0 + 16 * tt + 4 * loct);
#pragma unroll
    for (int e = 0; e < 4; ++e) {
      f32x4 v;
      v[0] = acc[tt][0][e] + bias4[e];
      v[1] = acc[tt][1][e] + bias4[e];
      v[2] = acc[tt][2][e] + bias4[e];
      v[3] = acc[tt][3][e] + bias4[e];  // tokens 4*lrow+0..3 of row rw0+16tt+4loct+e
      *(f32x4*)(epi_w + (4 * loct + e) * 68 + 4 * lrow) = v;
    }
    // wave-local ds_write -> ds_read ordered by program order, no barrier
#pragma unroll
    for (int h = 0; h < 4; ++h) {
      int r = 4 * h + loct;
      f32x4 v = *(const f32x4*)(epi_w + r * 68 + 4 * lrow);
      *(f32x4*)(ob + (size_t)(rbase + rw0 + 16 * tt + r) * NTOK + n0 + 4 * lrow) = v;
    }
  }
}

extern "C" void kernel_launch(void* const* d_in, const int* in_sizes, int n_in,
                              void* d_out, int out_size, void* d_ws, size_t ws_size,
                              hipStream_t stream) {
  const float* x = (const float*)d_in[0];
  const float* wqkv = (const float*)d_in[1];
  const float* wproj = (const float*)d_in[2];
  const float* bproj = (const float*)d_in[3];
  const float* temp = (const float*)d_in[4];
  float* out = (float*)d_out;

  const size_t GSZ = (size_t)NB * C_DIM * C_DIM;  // 589824 floats
  const size_t TSZ = (size_t)NB * 384 * C_DIM;    // 1179648 floats
  int nchunk = 32;
  while (nchunk > 1 &&
         ((size_t)nchunk * GSZ + GSZ + TSZ + GSZ + GSZ) * 4 > ws_size)
    nchunk >>= 1;
  float* wsf = (float*)d_ws;
  float* gpart = wsf;
  float* G = gpart + (size_t)nchunk * GSZ;
  float* Tt = G + GSZ;
  float* Yt = Tt + TSZ;
  __bf16* M = (__bf16*)(Yt + GSZ);

  k1_gram<<<dim3(nchunk, NB), 512, 0, stream>>>(x, gpart, NTOK / nchunk);
  k2a_reduce<<<dim3(576), 256, 0, stream>>>(gpart, G, nchunk);
  k2b1_t<<<dim3(6, NB), 256, 0, stream>>>(G, wqkv, Tt);
  k2b2_attn<<<dim3(NH, NB), 256, 0, stream>>>(Tt, wqkv, temp, Yt);
  k2c_m<<<dim3(3, NB), 256, 0, stream>>>(wproj, Yt, M);
  k3_out<<<dim3(2, NTOK / 128, NB), 256, 0, stream>>>(x, M, bproj, out);
}

// Round 9
// 232.234 us; speedup vs baseline: 1.2692x; 1.0763x over previous
//
#include <hip/hip_runtime.h>
#include <hip/hip_bf16.h>
#include <math.h>

#define C_DIM 192
#define NTOK 16384
#define NB 16
#define NH 8
#define HD 24
#define EPSN 1e-12f

typedef float f32x4 __attribute__((ext_vector_type(4)));
typedef __bf16 bf16x4 __attribute__((ext_vector_type(4)));
typedef __bf16 bf16x8 __attribute__((ext_vector_type(8)));

__device__ __forceinline__ f32x4 mfma16(bf16x8 a, bf16x8 b, f32x4 c) {
  return __builtin_amdgcn_mfma_f32_16x16x32_bf16(a, b, c, 0, 0, 0);
}

// load 8 consecutive f32 (16B-aligned x2) and convert to 8 bf16
__device__ __forceinline__ bf16x8 cvt8(const float* __restrict__ p) {
  f32x4 a = *(const f32x4*)p;
  f32x4 b = *(const f32x4*)(p + 4);
  bf16x8 r;
  r[0] = (__bf16)a[0]; r[1] = (__bf16)a[1]; r[2] = (__bf16)a[2]; r[3] = (__bf16)a[3];
  r[4] = (__bf16)b[0]; r[5] = (__bf16)b[1]; r[6] = (__bf16)b[2]; r[7] = (__bf16)b[3];
  return r;
}

// ---------------- K1: partial Gram, BK=64 staging (256B runs/row) -----------
// 2x192x72 bf16 LDS (55KB) dbuf; 8 stages of 64 k-cols; per stage each row is
// one 256B contiguous read (2x the old run length), half the barriers.
__global__ __launch_bounds__(256, 2) void k1_gram(const float* __restrict__ x,
                                                  float* __restrict__ gpart,
                                                  int kc) {
  const int b = blockIdx.y, chunk = blockIdx.x;
  const float* xb = x + (size_t)b * C_DIM * NTOK + (size_t)chunk * kc;
  __shared__ __bf16 xsh[2][C_DIM * 72];  // 2 x 27KB, stride 72 (2-way-free)
  const int t = threadIdx.x;
  const int lane = t & 63, wid = t >> 6;
  const int lrow = lane & 15, loct = lane >> 4;
  const int r0 = (wid >> 1) * 96, c0 = (wid & 1) * 96;
  f32x4 acc[6][6] = {};
  f32x4 stg[12];

  // prologue: stage k=0..63 into buf 0
#pragma unroll
  for (int it = 0; it < 12; ++it) {
    int idx = it * 256 + t, r = idx >> 4, c16 = idx & 15;
    stg[it] = *(const f32x4*)(xb + (size_t)r * NTOK + 4 * c16);
  }
#pragma unroll
  for (int it = 0; it < 12; ++it) {
    int idx = it * 256 + t, r = idx >> 4, c16 = idx & 15;
    bf16x4 w;
    w[0] = (__bf16)stg[it][0]; w[1] = (__bf16)stg[it][1];
    w[2] = (__bf16)stg[it][2]; w[3] = (__bf16)stg[it][3];
    *(bf16x4*)(&xsh[0][r * 72 + 4 * c16]) = w;
  }
  __syncthreads();

  for (int ks = 0; ks < kc; ks += 64) {
    const int cur = (ks >> 6) & 1;
    const bool more = (ks + 64) < kc;
    if (more) {
#pragma unroll
      for (int it = 0; it < 12; ++it) {
        int idx = it * 256 + t, r = idx >> 4, c16 = idx & 15;
        stg[it] = *(const f32x4*)(xb + (size_t)r * NTOK + ks + 64 + 4 * c16);
      }
    }
#pragma unroll
    for (int kk = 0; kk < 2; ++kk) {
      bf16x8 fa[6];
#pragma unroll
      for (int i = 0; i < 6; ++i)
        fa[i] = *(const bf16x8*)(&xsh[cur][(r0 + 16 * i + lrow) * 72 + 32 * kk +
                                           8 * loct]);
#pragma unroll
      for (int j = 0; j < 6; ++j) {
        bf16x8 fb = *(const bf16x8*)(&xsh[cur][(c0 + 16 * j + lrow) * 72 +
                                               32 * kk + 8 * loct]);
#pragma unroll
        for (int i = 0; i < 6; ++i) acc[i][j] = mfma16(fa[i], fb, acc[i][j]);
      }
    }
    if (more) {
#pragma unroll
      for (int it = 0; it < 12; ++it) {
        int idx = it * 256 + t, r = idx >> 4, c16 = idx & 15;
        bf16x4 w;
        w[0] = (__bf16)stg[it][0]; w[1] = (__bf16)stg[it][1];
        w[2] = (__bf16)stg[it][2]; w[3] = (__bf16)stg[it][3];
        *(bf16x4*)(&xsh[cur ^ 1][r * 72 + 4 * c16]) = w;
      }
    }
    __syncthreads();
  }
  float* gp = gpart + ((size_t)chunk * NB + b) * C_DIM * C_DIM;
#pragma unroll
  for (int i = 0; i < 6; ++i)
#pragma unroll
    for (int j = 0; j < 6; ++j)
#pragma unroll
      for (int e = 0; e < 4; ++e)
        gp[(size_t)(r0 + 16 * i + 4 * loct + e) * C_DIM + (c0 + 16 * j + lrow)] =
            acc[i][j][e];
}

// ---------------- K2a: reduce partials -> G ---------------------------------
__global__ __launch_bounds__(256) void k2a_reduce(const float* __restrict__ gpart,
                                                  float* __restrict__ G,
                                                  int nchunk) {
  const size_t total = (size_t)NB * C_DIM * C_DIM;
  size_t e0 = ((size_t)blockIdx.x * 256 + threadIdx.x) * 4;
  f32x4 s = {};
  for (int c = 0; c < nchunk; ++c) s += *(const f32x4*)(gpart + c * total + e0);
  *(f32x4*)(G + e0) = s;
}

// ---------------- K2b1: Tt[b] = [Wq|Wk]^T @ G  (384x192), uses G symmetry ---
__global__ __launch_bounds__(256) void k2b1_t(const float* __restrict__ G,
                                              const float* __restrict__ wqkv,
                                              float* __restrict__ Tt) {
  const int b = blockIdx.y, rb = blockIdx.x;  // rb 0..5 -> 64 rows
  const int lane = threadIdx.x & 63, wid = threadIdx.x >> 6;
  const int lrow = lane & 15, loct = lane >> 4;
  const float* Gb = G + (size_t)b * C_DIM * C_DIM;
  const int ddA = rb * 64 + wid * 16 + lrow;  // < 384, == wqkv column index
  f32x4 acc[12] = {};
  for (int s = 0; s < 6; ++s) {
    bf16x8 fa;
#pragma unroll
    for (int e = 0; e < 8; ++e)
      fa[e] = (__bf16)wqkv[(size_t)(32 * s + 8 * loct + e) * 576 + ddA];
#pragma unroll
    for (int j = 0; j < 12; ++j) {
      bf16x8 fb = cvt8(Gb + (size_t)(16 * j + lrow) * C_DIM + 32 * s + 8 * loct);
      acc[j] = mfma16(fa, fb, acc[j]);
    }
  }
  float* To = Tt + (size_t)b * 384 * C_DIM;
#pragma unroll
  for (int j = 0; j < 12; ++j)
#pragma unroll
    for (int e = 0; e < 4; ++e)
      To[(size_t)(rb * 64 + wid * 16 + 4 * loct + e) * C_DIM + 16 * j + lrow] =
          acc[j][e];
}

// ---------------- K2b2: per (b,h): S, norms, softmax, Yt -------------------
__global__ __launch_bounds__(256) void k2b2_attn(const float* __restrict__ Tt,
                                                 const float* __restrict__ wqkv,
                                                 const float* __restrict__ temp,
                                                 float* __restrict__ Yt) {
  const int b = blockIdx.y, h = blockIdx.x;
  __shared__ float SL[32][33];
  __shared__ float qn2L[HD], kn2L[HD];
  const int t = threadIdx.x;
  const int lane = t & 63, wid = t >> 6;
  const int lrow = lane & 15, loct = lane >> 4;
  const float* Tb = Tt + (size_t)b * 384 * C_DIM;
  const int r = wid >> 1, j = wid & 1;  // 2x2 tiles cover 32x32 (clip to 24x24)
  f32x4 acc = {};
  for (int s = 0; s < 6; ++s) {
    bf16x8 fa = cvt8(Tb + (size_t)(h * HD + 16 * r + lrow) * C_DIM + 32 * s + 8 * loct);
    bf16x8 fb;
#pragma unroll
    for (int e = 0; e < 8; ++e)
      fb[e] = (__bf16)wqkv[(size_t)(32 * s + 8 * loct + e) * 576 + 192 + h * HD +
                           16 * j + lrow];
    acc = mfma16(fa, fb, acc);
  }
#pragma unroll
  for (int e = 0; e < 4; ++e) {
    int d = 16 * r + 4 * loct + e, ee = 16 * j + lrow;
    if (d < HD && ee < HD) SL[d][ee] = acc[e];
  }
  if (t < 48) {  // squared norms: diag of Wq^T G Wq / Wk^T G Wk
    const int dd = (t < 24) ? t : t - 24;
    const int row = ((t < 24) ? 0 : 192) + h * HD + dd;
    float s = 0.f;
    for (int c = 0; c < C_DIM; ++c)
      s += Tb[(size_t)row * C_DIM + c] * wqkv[(size_t)c * 576 + row];
    if (t < 24) qn2L[dd] = s; else kn2L[dd] = s;
  }
  __syncthreads();
  if (t < HD) {  // softmax row t
    const float tp = temp[h];
    float nq = fmaxf(sqrtf(fmaxf(qn2L[t], 0.f)), EPSN);
    float lg[HD];
    float m = -1e30f;
#pragma unroll
    for (int e = 0; e < HD; ++e) {
      float nk = fmaxf(sqrtf(fmaxf(kn2L[e], 0.f)), EPSN);
      lg[e] = SL[t][e] / (nq * nk) * tp;
      m = fmaxf(m, lg[e]);
    }
    float sum = 0.f;
#pragma unroll
    for (int e = 0; e < HD; ++e) { lg[e] = __expf(lg[e] - m); sum += lg[e]; }
    float inv = 1.f / sum;
#pragma unroll
    for (int e = 0; e < HD; ++e) SL[t][e] = lg[e] * inv;
  }
  __syncthreads();
  if (t < C_DIM) {  // Yt[b][ci=t][h*24+d] = sum_e attn[d][e] * Wv[t][e]
    float wv[HD];
#pragma unroll
    for (int e = 0; e < HD; ++e)
      wv[e] = wqkv[(size_t)t * 576 + 384 + h * HD + e];
    float* Yo = Yt + ((size_t)b * C_DIM + t) * C_DIM + h * HD;
#pragma unroll
    for (int d = 0; d < HD; ++d) {
      float y = 0.f;
#pragma unroll
      for (int e = 0; e < HD; ++e) y += SL[d][e] * wv[e];
      Yo[d] = y;
    }
  }
}

// ---------------- K2c: M[b] = Wproj^T @ Y  (bf16 out) -----------------------
__global__ __launch_bounds__(256) void k2c_m(const float* __restrict__ wproj,
                                             const float* __restrict__ Yt,
                                             __bf16* __restrict__ M) {
  const int b = blockIdx.y, rb = blockIdx.x;  // rb 0..2 -> 64 rows
  const int lane = threadIdx.x & 63, wid = threadIdx.x >> 6;
  const int lrow = lane & 15, loct = lane >> 4;
  const float* Yb = Yt + (size_t)b * C_DIM * C_DIM;
  const int coA = rb * 64 + wid * 16 + lrow;
  f32x4 acc[12] = {};
  for (int s = 0; s < 6; ++s) {
    bf16x8 fa;
#pragma unroll
    for (int e = 0; e < 8; ++e)
      fa[e] = (__bf16)wproj[(size_t)(32 * s + 8 * loct + e) * C_DIM + coA];
#pragma unroll
    for (int j = 0; j < 12; ++j) {
      bf16x8 fb = cvt8(Yb + (size_t)(16 * j + lrow) * C_DIM + 32 * s + 8 * loct);
      acc[j] = mfma16(fa, fb, acc[j]);
    }
  }
  __bf16* Mo = M + (size_t)b * C_DIM * C_DIM;
#pragma unroll
  for (int j = 0; j < 12; ++j)
#pragma unroll
    for (int e = 0; e < 4; ++e)
      Mo[(size_t)(rb * 64 + wid * 16 + 4 * loct + e) * C_DIM + 16 * j + lrow] =
          (__bf16)acc[j][e];
}

// ---------------- K3 v6 (proven 95us): out[b] = M[b] @ x[b] + bias ----------
// Token-interleaved fragments; half-M in 36.8KB swizzled LDS; f32x4 x loads;
// per-wave LDS transpose epilogue -> dwordx4 store runs.
__global__ __launch_bounds__(256, 3) void k3_out(const float* __restrict__ x,
                                                 const __bf16* __restrict__ M,
                                                 const float* __restrict__ bproj,
                                                 float* __restrict__ out) {
  const int nt = blockIdx.x, half = blockIdx.y, b = blockIdx.z;
  const int rbase = half * 96;
  __shared__ __bf16 Ml[96 * C_DIM];  // 36864B; overlaid by epi after main loop
  __shared__ float biasL[96];
  const int t = threadIdx.x;
  const int lane = t & 63, w = t >> 6;
  const int lrow = lane & 15, loct = lane >> 4;

  const __bf16* Mb = M + (size_t)b * C_DIM * C_DIM + (size_t)rbase * C_DIM;
  for (int i = t; i < 96 * 24; i += 256) {
    int row = i / 24, ch = i % 24;
    bf16x8 v = *(const bf16x8*)(Mb + row * C_DIM + ch * 8);
    *(bf16x8*)(Ml + row * C_DIM + ((ch ^ (row & 7)) * 8)) = v;
  }
  if (t < 96) biasL[t] = bproj[rbase + t];
  __syncthreads();

  const float* xb = x + (size_t)b * C_DIM * NTOK;
  float* ob = out + (size_t)b * C_DIM * NTOK;
  const int n0 = nt * 256 + w * 64;  // wave's 64-token window

  f32x4 acc[6][4] = {};
  f32x4 xs4[8];  // prefetch: slab's 8 channels x 4 consecutive tokens
#pragma unroll
  for (int e = 0; e < 8; ++e)
    xs4[e] = *(const f32x4*)(xb + (size_t)(8 * loct + e) * NTOK + n0 + 4 * lrow);

  for (int s = 0; s < 6; ++s) {
    bf16x8 fb[4];  // fb[nf][e] = x[ch=32s+8loct+e][tok=n0+4*lrow+nf]
#pragma unroll
    for (int nf = 0; nf < 4; ++nf)
#pragma unroll
      for (int e = 0; e < 8; ++e)
        fb[nf][e] = (__bf16)xs4[e][nf];
    if (s < 5) {
#pragma unroll
      for (int e = 0; e < 8; ++e)
        xs4[e] = *(const f32x4*)(xb + (size_t)(32 * (s + 1) + 8 * loct + e) * NTOK +
                                 n0 + 4 * lrow);
    }
#pragma unroll
    for (int tt = 0; tt < 6; ++tt) {
      int rowb = 16 * tt + lrow;
      bf16x8 fa = *(const bf16x8*)(Ml + rowb * C_DIM +
                                   (((4 * s + loct) ^ (rowb & 7)) * 8));
#pragma unroll
      for (int nf = 0; nf < 4; ++nf)
        acc[tt][nf] = mfma16(fa, fb[nf], acc[tt][nf]);
    }
  }

  __syncthreads();  // all waves done reading Ml; safe to overlay epi
  // per-wave transpose buffer: 16 rows x 64 tokens, stride 68 f32
  float* epi_w = (float*)Ml + w * 1088;
#pragma unroll
  for (int tt = 0; tt < 6; ++tt) {
    f32x4 bias4 = *(const f32x4*)(biasL + 16 * tt + 4 * loct);  // rows 4loct+e
#pragma unroll
    for (int e = 0; e < 4; ++e) {
      f32x4 v;
      v[0] = acc[tt][0][e] + bias4[e];
      v[1] = acc[tt][1][e] + bias4[e];
      v[2] = acc[tt][2][e] + bias4[e];
      v[3] = acc[tt][3][e] + bias4[e];  // tokens 4*lrow+0..3 of row 16tt+4loct+e
      *(f32x4*)(epi_w + (4 * loct + e) * 68 + 4 * lrow) = v;
    }
    // wave-local ds_write -> ds_read ordered by program order, no barrier
#pragma unroll
    for (int h = 0; h < 4; ++h) {
      int r = 4 * h + loct;
      f32x4 v = *(const f32x4*)(epi_w + r * 68 + 4 * lrow);
      *(f32x4*)(ob + (size_t)(rbase + 16 * tt + r) * NTOK + n0 + 4 * lrow) = v;
    }
  }
}

extern "C" void kernel_launch(void* const* d_in, const int* in_sizes, int n_in,
                              void* d_out, int out_size, void* d_ws, size_t ws_size,
                              hipStream_t stream) {
  const float* x = (const float*)d_in[0];
  const float* wqkv = (const float*)d_in[1];
  const float* wproj = (const float*)d_in[2];
  const float* bproj = (const float*)d_in[3];
  const float* temp = (const float*)d_in[4];
  float* out = (float*)d_out;

  const size_t GSZ = (size_t)NB * C_DIM * C_DIM;  // 589824 floats
  const size_t TSZ = (size_t)NB * 384 * C_DIM;    // 1179648 floats
  int nchunk = 32;
  while (nchunk > 1 &&
         ((size_t)nchunk * GSZ + GSZ + TSZ + GSZ + GSZ) * 4 > ws_size)
    nchunk >>= 1;
  float* wsf = (float*)d_ws;
  float* gpart = wsf;
  float* G = gpart + (size_t)nchunk * GSZ;
  float* Tt = G + GSZ;
  float* Yt = Tt + TSZ;
  __bf16* M = (__bf16*)(Yt + GSZ);

  k1_gram<<<dim3(nchunk, NB), 256, 0, stream>>>(x, gpart, NTOK / nchunk);
  k2a_reduce<<<dim3(576), 256, 0, stream>>>(gpart, G, nchunk);
  k2b1_t<<<dim3(6, NB), 256, 0, stream>>>(G, wqkv, Tt);
  k2b2_attn<<<dim3(NH, NB), 256, 0, stream>>>(Tt, wqkv, temp, Yt);
  k2c_m<<<dim3(3, NB), 256, 0, stream>>>(wproj, Yt, M);
  k3_out<<<dim3(NTOK / 256, 2, NB), 256, 0, stream>>>(x, M, bproj, out);
}

// Round 10
// 226.867 us; speedup vs baseline: 1.2993x; 1.0237x over previous
//
#include <hip/hip_runtime.h>
#include <hip/hip_bf16.h>
#include <math.h>

#define C_DIM 192
#define NTOK 16384
#define NB 16
#define NH 8
#define HD 24
#define EPSN 1e-12f

typedef float f32x4 __attribute__((ext_vector_type(4)));
typedef __bf16 bf16x4 __attribute__((ext_vector_type(4)));
typedef __bf16 bf16x8 __attribute__((ext_vector_type(8)));

__device__ __forceinline__ f32x4 mfma16(bf16x8 a, bf16x8 b, f32x4 c) {
  return __builtin_amdgcn_mfma_f32_16x16x32_bf16(a, b, c, 0, 0, 0);
}

// load 8 consecutive f32 (16B-aligned x2) and convert to 8 bf16
__device__ __forceinline__ bf16x8 cvt8(const float* __restrict__ p) {
  f32x4 a = *(const f32x4*)p;
  f32x4 b = *(const f32x4*)(p + 4);
  bf16x8 r;
  r[0] = (__bf16)a[0]; r[1] = (__bf16)a[1]; r[2] = (__bf16)a[2]; r[3] = (__bf16)a[3];
  r[4] = (__bf16)b[0]; r[5] = (__bf16)b[1]; r[6] = (__bf16)b[2]; r[7] = (__bf16)b[3];
  return r;
}

// ---------------- K1: partial Gram, depth-2 staging pipeline ----------------
// Two load batches in flight (sA/sB), 2 LDS buffers, loop unrolled x2:
// loads(s+2) issue at top of step s, ds_write one step later -> in-flight
// window ~2 compute phases, covering HBM tail latency that the old depth-1
// barrier-locked loop re-exposed every step.
__global__ __launch_bounds__(256, 2) void k1_gram(const float* __restrict__ x,
                                                  float* __restrict__ gpart,
                                                  int kc) {
  const int b = blockIdx.y, chunk = blockIdx.x;
  const float* xb = x + (size_t)b * C_DIM * NTOK + (size_t)chunk * kc;
  __shared__ __bf16 xsh[2][C_DIM * 40];  // 2 x 15KB, stride 40
  const int t = threadIdx.x;
  const int lane = t & 63, wid = t >> 6;
  const int lrow = lane & 15, loct = lane >> 4;
  const int r0 = (wid >> 1) * 96, c0 = (wid & 1) * 96;
  f32x4 acc[6][6] = {};
  f32x4 sA[6], sB[6];
  const int nst = kc >> 5;  // 16 at nchunk=32

#define K1_LOADR(dst, ks)                                                      \
  {                                                                            \
    _Pragma("unroll") for (int it = 0; it < 6; ++it) {                         \
      int idx = it * 256 + t, r = idx >> 3, c8 = idx & 7;                      \
      dst[it] = *(const f32x4*)(xb + (size_t)r * NTOK + (ks) + 4 * c8);        \
    }                                                                          \
  }
#define K1_STORE(buf, src)                                                     \
  {                                                                            \
    _Pragma("unroll") for (int it = 0; it < 6; ++it) {                         \
      int idx = it * 256 + t, r = idx >> 3, c8 = idx & 7;                      \
      bf16x4 w;                                                                \
      w[0] = (__bf16)src[it][0]; w[1] = (__bf16)src[it][1];                    \
      w[2] = (__bf16)src[it][2]; w[3] = (__bf16)src[it][3];                    \
      *(bf16x4*)(&xsh[buf][r * 40 + 4 * c8]) = w;                              \
    }                                                                          \
  }
#define K1_COMP(buf)                                                           \
  {                                                                            \
    bf16x8 fa[6];                                                              \
    _Pragma("unroll") for (int i = 0; i < 6; ++i)                              \
        fa[i] = *(const bf16x8*)(&xsh[buf][(r0 + 16 * i + lrow) * 40 +         \
                                           8 * loct]);                         \
    _Pragma("unroll") for (int j = 0; j < 6; ++j) {                            \
      bf16x8 fb =                                                              \
          *(const bf16x8*)(&xsh[buf][(c0 + 16 * j + lrow) * 40 + 8 * loct]);   \
      _Pragma("unroll") for (int i = 0; i < 6; ++i)                            \
          acc[i][j] = mfma16(fa[i], fb, acc[i][j]);                            \
    }                                                                          \
  }

  K1_LOADR(sA, 0);      // data(0)
  K1_STORE(0, sA);      // lds0 = data(0)
  K1_LOADR(sB, 32);     // data(1) in flight
  __syncthreads();

  for (int s = 0; s < nst; s += 2) {
    if (s + 2 < nst) K1_LOADR(sA, 32 * (s + 2));  // data(s+2) in flight
    K1_COMP(0);                                   // compute data(s)
    K1_STORE(1, sB);                              // lds1 = data(s+1)
    __syncthreads();
    if (s + 3 < nst) K1_LOADR(sB, 32 * (s + 3));  // data(s+3) in flight
    K1_COMP(1);                                   // compute data(s+1)
    if (s + 2 < nst) K1_STORE(0, sA);             // lds0 = data(s+2)
    __syncthreads();
  }
#undef K1_LOADR
#undef K1_STORE
#undef K1_COMP

  float* gp = gpart + ((size_t)chunk * NB + b) * C_DIM * C_DIM;
#pragma unroll
  for (int i = 0; i < 6; ++i)
#pragma unroll
    for (int j = 0; j < 6; ++j)
#pragma unroll
      for (int e = 0; e < 4; ++e)
        gp[(size_t)(r0 + 16 * i + 4 * loct + e) * C_DIM + (c0 + 16 * j + lrow)] =
            acc[i][j][e];
}

// ---------------- K2a: reduce partials -> G ---------------------------------
__global__ __launch_bounds__(256) void k2a_reduce(const float* __restrict__ gpart,
                                                  float* __restrict__ G,
                                                  int nchunk) {
  const size_t total = (size_t)NB * C_DIM * C_DIM;
  size_t e0 = ((size_t)blockIdx.x * 256 + threadIdx.x) * 4;
  f32x4 s = {};
  for (int c = 0; c < nchunk; ++c) s += *(const f32x4*)(gpart + c * total + e0);
  *(f32x4*)(G + e0) = s;
}

// ---------------- K2b1: Tt[b] = [Wq|Wk]^T @ G  (384x192), uses G symmetry ---
__global__ __launch_bounds__(256) void k2b1_t(const float* __restrict__ G,
                                              const float* __restrict__ wqkv,
                                              float* __restrict__ Tt) {
  const int b = blockIdx.y, rb = blockIdx.x;  // rb 0..5 -> 64 rows
  const int lane = threadIdx.x & 63, wid = threadIdx.x >> 6;
  const int lrow = lane & 15, loct = lane >> 4;
  const float* Gb = G + (size_t)b * C_DIM * C_DIM;
  const int ddA = rb * 64 + wid * 16 + lrow;  // < 384, == wqkv column index
  f32x4 acc[12] = {};
  for (int s = 0; s < 6; ++s) {
    bf16x8 fa;
#pragma unroll
    for (int e = 0; e < 8; ++e)
      fa[e] = (__bf16)wqkv[(size_t)(32 * s + 8 * loct + e) * 576 + ddA];
#pragma unroll
    for (int j = 0; j < 12; ++j) {
      bf16x8 fb = cvt8(Gb + (size_t)(16 * j + lrow) * C_DIM + 32 * s + 8 * loct);
      acc[j] = mfma16(fa, fb, acc[j]);
    }
  }
  float* To = Tt + (size_t)b * 384 * C_DIM;
#pragma unroll
  for (int j = 0; j < 12; ++j)
#pragma unroll
    for (int e = 0; e < 4; ++e)
      To[(size_t)(rb * 64 + wid * 16 + 4 * loct + e) * C_DIM + 16 * j + lrow] =
          acc[j][e];
}

// ---------------- K2b2: per (b,h): S, norms, softmax, Yt -------------------
__global__ __launch_bounds__(256) void k2b2_attn(const float* __restrict__ Tt,
                                                 const float* __restrict__ wqkv,
                                                 const float* __restrict__ temp,
                                                 float* __restrict__ Yt) {
  const int b = blockIdx.y, h = blockIdx.x;
  __shared__ float SL[32][33];
  __shared__ float qn2L[HD], kn2L[HD];
  const int t = threadIdx.x;
  const int lane = t & 63, wid = t >> 6;
  const int lrow = lane & 15, loct = lane >> 4;
  const float* Tb = Tt + (size_t)b * 384 * C_DIM;
  const int r = wid >> 1, j = wid & 1;  // 2x2 tiles cover 32x32 (clip to 24x24)
  f32x4 acc = {};
  for (int s = 0; s < 6; ++s) {
    bf16x8 fa = cvt8(Tb + (size_t)(h * HD + 16 * r + lrow) * C_DIM + 32 * s + 8 * loct);
    bf16x8 fb;
#pragma unroll
    for (int e = 0; e < 8; ++e)
      fb[e] = (__bf16)wqkv[(size_t)(32 * s + 8 * loct + e) * 576 + 192 + h * HD +
                           16 * j + lrow];
    acc = mfma16(fa, fb, acc);
  }
#pragma unroll
  for (int e = 0; e < 4; ++e) {
    int d = 16 * r + 4 * loct + e, ee = 16 * j + lrow;
    if (d < HD && ee < HD) SL[d][ee] = acc[e];
  }
  if (t < 48) {  // squared norms: diag of Wq^T G Wq / Wk^T G Wk
    const int dd = (t < 24) ? t : t - 24;
    const int row = ((t < 24) ? 0 : 192) + h * HD + dd;
    float s = 0.f;
    for (int c = 0; c < C_DIM; ++c)
      s += Tb[(size_t)row * C_DIM + c] * wqkv[(size_t)c * 576 + row];
    if (t < 24) qn2L[dd] = s; else kn2L[dd] = s;
  }
  __syncthreads();
  if (t < HD) {  // softmax row t
    const float tp = temp[h];
    float nq = fmaxf(sqrtf(fmaxf(qn2L[t], 0.f)), EPSN);
    float lg[HD];
    float m = -1e30f;
#pragma unroll
    for (int e = 0; e < HD; ++e) {
      float nk = fmaxf(sqrtf(fmaxf(kn2L[e], 0.f)), EPSN);
      lg[e] = SL[t][e] / (nq * nk) * tp;
      m = fmaxf(m, lg[e]);
    }
    float sum = 0.f;
#pragma unroll
    for (int e = 0; e < HD; ++e) { lg[e] = __expf(lg[e] - m); sum += lg[e]; }
    float inv = 1.f / sum;
#pragma unroll
    for (int e = 0; e < HD; ++e) SL[t][e] = lg[e] * inv;
  }
  __syncthreads();
  if (t < C_DIM) {  // Yt[b][ci=t][h*24+d] = sum_e attn[d][e] * Wv[t][e]
    float wv[HD];
#pragma unroll
    for (int e = 0; e < HD; ++e)
      wv[e] = wqkv[(size_t)t * 576 + 384 + h * HD + e];
    float* Yo = Yt + ((size_t)b * C_DIM + t) * C_DIM + h * HD;
#pragma unroll
    for (int d = 0; d < HD; ++d) {
      float y = 0.f;
#pragma unroll
      for (int e = 0; e < HD; ++e) y += SL[d][e] * wv[e];
      Yo[d] = y;
    }
  }
}

// ---------------- K2c: M[b] = Wproj^T @ Y  (bf16 out) -----------------------
__global__ __launch_bounds__(256) void k2c_m(const float* __restrict__ wproj,
                                             const float* __restrict__ Yt,
                                             __bf16* __restrict__ M) {
  const int b = blockIdx.y, rb = blockIdx.x;  // rb 0..2 -> 64 rows
  const int lane = threadIdx.x & 63, wid = threadIdx.x >> 6;
  const int lrow = lane & 15, loct = lane >> 4;
  const float* Yb = Yt + (size_t)b * C_DIM * C_DIM;
  const int coA = rb * 64 + wid * 16 + lrow;
  f32x4 acc[12] = {};
  for (int s = 0; s < 6; ++s) {
    bf16x8 fa;
#pragma unroll
    for (int e = 0; e < 8; ++e)
      fa[e] = (__bf16)wproj[(size_t)(32 * s + 8 * loct + e) * C_DIM + coA];
#pragma unroll
    for (int j = 0; j < 12; ++j) {
      bf16x8 fb = cvt8(Yb + (size_t)(16 * j + lrow) * C_DIM + 32 * s + 8 * loct);
      acc[j] = mfma16(fa, fb, acc[j]);
    }
  }
  __bf16* Mo = M + (size_t)b * C_DIM * C_DIM;
#pragma unroll
  for (int j = 0; j < 12; ++j)
#pragma unroll
    for (int e = 0; e < 4; ++e)
      Mo[(size_t)(rb * 64 + wid * 16 + 4 * loct + e) * C_DIM + 16 * j + lrow] =
          (__bf16)acc[j][e];
}

// ---------------- K3 v6 (proven 95us): out[b] = M[b] @ x[b] + bias ----------
// Token-interleaved fragments; half-M in 36.8KB swizzled LDS; f32x4 x loads;
// per-wave LDS transpose epilogue -> dwordx4 store runs.
__global__ __launch_bounds__(256, 3) void k3_out(const float* __restrict__ x,
                                                 const __bf16* __restrict__ M,
                                                 const float* __restrict__ bproj,
                                                 float* __restrict__ out) {
  const int nt = blockIdx.x, half = blockIdx.y, b = blockIdx.z;
  const int rbase = half * 96;
  __shared__ __bf16 Ml[96 * C_DIM];  // 36864B; overlaid by epi after main loop
  __shared__ float biasL[96];
  const int t = threadIdx.x;
  const int lane = t & 63, w = t >> 6;
  const int lrow = lane & 15, loct = lane >> 4;

  const __bf16* Mb = M + (size_t)b * C_DIM * C_DIM + (size_t)rbase * C_DIM;
  for (int i = t; i < 96 * 24; i += 256) {
    int row = i / 24, ch = i % 24;
    bf16x8 v = *(const bf16x8*)(Mb + row * C_DIM + ch * 8);
    *(bf16x8*)(Ml + row * C_DIM + ((ch ^ (row & 7)) * 8)) = v;
  }
  if (t < 96) biasL[t] = bproj[rbase + t];
  __syncthreads();

  const float* xb = x + (size_t)b * C_DIM * NTOK;
  float* ob = out + (size_t)b * C_DIM * NTOK;
  const int n0 = nt * 256 + w * 64;  // wave's 64-token window

  f32x4 acc[6][4] = {};
  f32x4 xs4[8];  // prefetch: slab's 8 channels x 4 consecutive tokens
#pragma unroll
  for (int e = 0; e < 8; ++e)
    xs4[e] = *(const f32x4*)(xb + (size_t)(8 * loct + e) * NTOK + n0 + 4 * lrow);

  for (int s = 0; s < 6; ++s) {
    bf16x8 fb[4];  // fb[nf][e] = x[ch=32s+8loct+e][tok=n0+4*lrow+nf]
#pragma unroll
    for (int nf = 0; nf < 4; ++nf)
#pragma unroll
      for (int e = 0; e < 8; ++e)
        fb[nf][e] = (__bf16)xs4[e][nf];
    if (s < 5) {
#pragma unroll
      for (int e = 0; e < 8; ++e)
        xs4[e] = *(const f32x4*)(xb + (size_t)(32 * (s + 1) + 8 * loct + e) * NTOK +
                                 n0 + 4 * lrow);
    }
#pragma unroll
    for (int tt = 0; tt < 6; ++tt) {
      int rowb = 16 * tt + lrow;
      bf16x8 fa = *(const bf16x8*)(Ml + rowb * C_DIM +
                                   (((4 * s + loct) ^ (rowb & 7)) * 8));
#pragma unroll
      for (int nf = 0; nf < 4; ++nf)
        acc[tt][nf] = mfma16(fa, fb[nf], acc[tt][nf]);
    }
  }

  __syncthreads();  // all waves done reading Ml; safe to overlay epi
  // per-wave transpose buffer: 16 rows x 64 tokens, stride 68 f32
  float* epi_w = (float*)Ml + w * 1088;
#pragma unroll
  for (int tt = 0; tt < 6; ++tt) {
    f32x4 bias4 = *(const f32x4*)(biasL + 16 * tt + 4 * loct);  // rows 4loct+e
#pragma unroll
    for (int e = 0; e < 4; ++e) {
      f32x4 v;
      v[0] = acc[tt][0][e] + bias4[e];
      v[1] = acc[tt][1][e] + bias4[e];
      v[2] = acc[tt][2][e] + bias4[e];
      v[3] = acc[tt][3][e] + bias4[e];  // tokens 4*lrow+0..3 of row 16tt+4loct+e
      *(f32x4*)(epi_w + (4 * loct + e) * 68 + 4 * lrow) = v;
    }
    // wave-local ds_write -> ds_read ordered by program order, no barrier
#pragma unroll
    for (int h = 0; h < 4; ++h) {
      int r = 4 * h + loct;
      f32x4 v = *(const f32x4*)(epi_w + r * 68 + 4 * lrow);
      *(f32x4*)(ob + (size_t)(rbase + 16 * tt + r) * NTOK + n0 + 4 * lrow) = v;
    }
  }
}

extern "C" void kernel_launch(void* const* d_in, const int* in_sizes, int n_in,
                              void* d_out, int out_size, void* d_ws, size_t ws_size,
                              hipStream_t stream) {
  const float* x = (const float*)d_in[0];
  const float* wqkv = (const float*)d_in[1];
  const float* wproj = (const float*)d_in[2];
  const float* bproj = (const float*)d_in[3];
  const float* temp = (const float*)d_in[4];
  float* out = (float*)d_out;

  const size_t GSZ = (size_t)NB * C_DIM * C_DIM;  // 589824 floats
  const size_t TSZ = (size_t)NB * 384 * C_DIM;    // 1179648 floats
  int nchunk = 32;
  while (nchunk > 1 &&
         ((size_t)nchunk * GSZ + GSZ + TSZ + GSZ + GSZ) * 4 > ws_size)
    nchunk >>= 1;
  float* wsf = (float*)d_ws;
  float* gpart = wsf;
  float* G = gpart + (size_t)nchunk * GSZ;
  float* Tt = G + GSZ;
  float* Yt = Tt + TSZ;
  __bf16* M = (__bf16*)(Yt + GSZ);

  k1_gram<<<dim3(nchunk, NB), 256, 0, stream>>>(x, gpart, NTOK / nchunk);
  k2a_reduce<<<dim3(576), 256, 0, stream>>>(gpart, G, nchunk);
  k2b1_t<<<dim3(6, NB), 256, 0, stream>>>(G, wqkv, Tt);
  k2b2_attn<<<dim3(NH, NB), 256, 0, stream>>>(Tt, wqkv, temp, Yt);
  k2c_m<<<dim3(3, NB), 256, 0, stream>>>(wproj, Yt, M);
  k3_out<<<dim3(NTOK / 256, 2, NB), 256, 0, stream>>>(x, M, bproj, out);
}